// Round 9
// baseline (143.677 us; speedup 1.0000x reference)
//
#include <hip/hip_runtime.h>

#define B_SZ 8
#define L_SEQ 144
#define NTOK 1152
#define D_MODEL 256
#define D_INNER 512
#define D_STATE 64
#define DT_RANK 4
#define NDBC 132

typedef __attribute__((ext_vector_type(8))) short bf16x8;
typedef __attribute__((ext_vector_type(4))) float f32x4;

// fp32 -> bf16-split (hi = RNE bf16, lo = trunc bf16 of residual), packed
// into int4 pairs for 16B LDS/register traffic.
__device__ __forceinline__ void cvt8(const float4& f0, const float4& f1,
                                     int4& hi, int4& lo) {
    const float f[8] = {f0.x, f0.y, f0.z, f0.w, f1.x, f1.y, f1.z, f1.w};
    unsigned h[8], l[8];
#pragma unroll
    for (int e = 0; e < 8; ++e) {
        const unsigned u = __float_as_uint(f[e]);
        const unsigned t = u + 0x7FFFu + ((u >> 16) & 1u);
        h[e] = t >> 16;
        l[e] = __float_as_uint(f[e] - __uint_as_float(t & 0xFFFF0000u)) >> 16;
    }
    hi = make_int4((int)(h[0] | (h[1] << 16)), (int)(h[2] | (h[3] << 16)),
                   (int)(h[4] | (h[5] << 16)), (int)(h[6] | (h[7] << 16)));
    lo = make_int4((int)(l[0] | (l[1] << 16)), (int)(l[2] | (l[3] << 16)),
                   (int)(l[4] | (l[5] << 16)), (int)(l[6] | (l[7] << 16)));
}

// unpack 8 packed u32 (hi<<16|lo) into hi/lo bf16x8 fragments
__device__ __forceinline__ void unpack8(const int4& p0, const int4& p1,
                                        bf16x8& hv, bf16x8& lv) {
    const unsigned u[8] = {(unsigned)p0.x, (unsigned)p0.y, (unsigned)p0.z,
                           (unsigned)p0.w, (unsigned)p1.x, (unsigned)p1.y,
                           (unsigned)p1.z, (unsigned)p1.w};
    int h[4], l[4];
#pragma unroll
    for (int i = 0; i < 4; ++i) {
        h[i] = (int)((u[2 * i] >> 16) | (u[2 * i + 1] & 0xFFFF0000u));
        l[i] = (int)((u[2 * i] & 0xFFFFu) | (u[2 * i + 1] << 16));
    }
    hv = *(bf16x8*)h;
    lv = *(bf16x8*)l;
}

__device__ __forceinline__ int bc_perm(const int p) {
    // stored position p -> original W_x row ([dt(4) | B0 C0 B1 C1 ...])
    return (p < DT_RANK) ? p
         : (((p - DT_RANK) & 1) ? (DT_RANK + D_STATE + ((p - DT_RANK) >> 1))
                                : (DT_RANK + ((p - DT_RANK) >> 1)));
}

// ---------------------------------------------------------------------------
// gemm1 (MFMA): xz[e][tok] = W_in[e][:] · x[tok][:]   M=1024 N=1152 K=256
// bf16-split-3: D = Ah·Bh + Ah·Bl + Al·Bh, fp32 accumulate. (R7/R8-verified)
// ---------------------------------------------------------------------------
#define LW 40
__global__ __launch_bounds__(256) void gemm1_mfma(const float* __restrict__ W_in,
                                                  const float* __restrict__ x,
                                                  float* __restrict__ xz) {
    __shared__ unsigned short Ah[64][LW], Al[64][LW], Bh[64][LW], Bl[64][LW];
    const int tid = threadIdx.x;
    const int m0 = blockIdx.y * 64, n0 = blockIdx.x * 64;
    const int r = tid >> 2, kq = (tid & 3) * 8;        // staging: row, k-offset
    const int w = tid >> 6, lane = tid & 63;
    const int wm = (w & 1) * 32, wn = (w >> 1) * 32;   // wave tile origin
    const int fr = lane & 15, fk = (lane >> 4) * 8;    // fragment row / k-group
    f32x4 acc[2][2] = {};
    float4 a0, a1, b0, b1;

    auto loadG = [&](const int k0) {
        const float* ap = W_in + (size_t)(m0 + r) * D_MODEL + k0 + kq;
        const float* bp = x    + (size_t)(n0 + r) * D_MODEL + k0 + kq;
        a0 = *(const float4*)ap; a1 = *(const float4*)(ap + 4);
        b0 = *(const float4*)bp; b1 = *(const float4*)(bp + 4);
    };

    loadG(0);
    for (int k0 = 0; k0 < D_MODEL; k0 += 32) {
        int4 hi, lo;
        __syncthreads();
        cvt8(a0, a1, hi, lo);
        *(int4*)&Ah[r][kq] = hi; *(int4*)&Al[r][kq] = lo;
        cvt8(b0, b1, hi, lo);
        *(int4*)&Bh[r][kq] = hi; *(int4*)&Bl[r][kq] = lo;
        __syncthreads();
        if (k0 + 32 < D_MODEL) loadG(k0 + 32);   // register prefetch
        bf16x8 ah[2], al[2], bh[2], bl[2];
#pragma unroll
        for (int i = 0; i < 2; ++i) {
            ah[i] = *(const bf16x8*)&Ah[wm + 16 * i + fr][fk];
            al[i] = *(const bf16x8*)&Al[wm + 16 * i + fr][fk];
            bh[i] = *(const bf16x8*)&Bh[wn + 16 * i + fr][fk];
            bl[i] = *(const bf16x8*)&Bl[wn + 16 * i + fr][fk];
        }
#pragma unroll
        for (int i = 0; i < 2; ++i)
#pragma unroll
            for (int j = 0; j < 2; ++j) {
                acc[i][j] = __builtin_amdgcn_mfma_f32_16x16x32_bf16(ah[i], bh[j], acc[i][j], 0, 0, 0);
                acc[i][j] = __builtin_amdgcn_mfma_f32_16x16x32_bf16(ah[i], bl[j], acc[i][j], 0, 0, 0);
                acc[i][j] = __builtin_amdgcn_mfma_f32_16x16x32_bf16(al[i], bh[j], acc[i][j], 0, 0, 0);
            }
    }
    const int orow = (lane >> 4) * 4;   // C/D: col = lane&15, row = (lane>>4)*4+reg
#pragma unroll
    for (int i = 0; i < 2; ++i)
#pragma unroll
        for (int j = 0; j < 2; ++j)
#pragma unroll
            for (int q = 0; q < 4; ++q)
                xz[(size_t)(m0 + wm + 16 * i + orow + q) * NTOK
                   + n0 + wn + 16 * j + fr] = acc[i][j][q];
}

// ---------------------------------------------------------------------------
// gemm2 (MFMA, wave-split-K): dBC[tok][p] = silu(conv(xz))[tok][:] · W_x[perm(p)][:]
// M=1152(tok) N=132(GN) K=512(d). Grid (3,18); wave w owns k in [128w,128w+128)
// (4 k-steps of 32) with its OWN LDS staging slice -> no barriers in the main
// loop (same-wave LDS write->read is in-order; precedent: scan's P array).
// Epilogue: cross-wave LDS reduce (left-assoc w0+w1+w2+w3) -> dBC directly.
// Conv+SiLU staging chain and PERM are bit-exact copies of R8's gemm2.
// ---------------------------------------------------------------------------
__global__ __launch_bounds__(256) void gemm2_mfma(const float* __restrict__ xz,
                                                  const float* __restrict__ W_x,
                                                  float* __restrict__ dBC,
                                                  const float* __restrict__ cw,
                                                  const float* __restrict__ cb) {
    __shared__ union {
        unsigned short st[4][4][64][LW];   // [wave][Ah,Al,Bh,Bl][row][col] 80 KB
        float red[4][4096];                // epilogue cross-wave buffer (64 KB)
    } sm;
    const int tid = threadIdx.x;
    const int n0 = blockIdx.x * 64;      // e-cols (0,64,128)
    const int m0 = blockIdx.y * 64;      // toks
    const int w = tid >> 6, lane = tid & 63;
    const int kw = w * 128;              // this wave's k-slab
    const int fr = lane & 15, fk = (lane >> 4) * 8;
    f32x4 acc[4][4] = {};

    float apre[4][11];                   // prefetched conv inputs (4 jobs/lane)
    float4 cwp[4];
    float cbp[4];

    auto loadA = [&](const int k0) {
#pragma unroll
        for (int jj = 0; jj < 4; ++jj) {
            const int id = jj * 64 + lane;
            const int dl = id >> 3, oct = id & 7;
            const int d = k0 + dl;
            const float* row = xz + (size_t)d * NTOK + m0 + oct * 8;
            const int t = (m0 + oct * 8) % L_SEQ;   // octet never straddles a seq
            apre[jj][0] = (t > 0) ? row[-2] : 0.f;            // left pad
            apre[jj][1] = (t > 0) ? row[-1] : 0.f;
            const float4 r0 = *(const float4*)row;
            const float4 r1 = *(const float4*)(row + 4);
            apre[jj][2] = r0.x; apre[jj][3] = r0.y; apre[jj][4] = r0.z; apre[jj][5] = r0.w;
            apre[jj][6] = r1.x; apre[jj][7] = r1.y; apre[jj][8] = r1.z; apre[jj][9] = r1.w;
            apre[jj][10] = (t < L_SEQ - 8) ? row[8] : 0.f;    // right pad
            cwp[jj] = *(const float4*)(cw + d * 4);
            cbp[jj] = cb[d];
        }
    };

    loadA(kw);
#pragma unroll
    for (int m = 0; m < 4; ++m) {
        const int k0 = kw + m * 32;
        // STAGE A: conv(4)+SiLU+bf16-split from prefetched regs, transposed 2B writes
#pragma unroll
        for (int jj = 0; jj < 4; ++jj) {
            const int id = jj * 64 + lane;
            const int dl = id >> 3, oct = id & 7;
#pragma unroll
            for (int j = 0; j < 8; ++j) {
                float s = cbp[jj];
                s = fmaf(cwp[jj].x, apre[jj][j + 0], s);
                s = fmaf(cwp[jj].y, apre[jj][j + 1], s);
                s = fmaf(cwp[jj].z, apre[jj][j + 2], s);
                s = fmaf(cwp[jj].w, apre[jj][j + 3], s);
                const float g = s * __builtin_amdgcn_rcpf(1.f + __expf(-s));
                const unsigned u = __float_as_uint(g);
                const unsigned tt = u + 0x7FFFu + ((u >> 16) & 1u);
                sm.st[w][0][oct * 8 + j][dl] = (unsigned short)(tt >> 16);
                sm.st[w][1][oct * 8 + j][dl] = (unsigned short)(__float_as_uint(
                    g - __uint_as_float(tt & 0xFFFF0000u)) >> 16);
            }
        }
        // STAGE B: W_x rows (PERM interleave), cvt8, int4 writes
#pragma unroll
        for (int jj = 0; jj < 4; ++jj) {
            const int id = jj * 64 + lane;
            const int e = id >> 2, ko = (id & 3) * 8;
            float4 b0 = make_float4(0.f, 0.f, 0.f, 0.f), b1 = b0;
            if (n0 + e < NDBC) {
                const float* bp = W_x + (size_t)bc_perm(n0 + e) * D_INNER + k0 + ko;
                b0 = *(const float4*)bp; b1 = *(const float4*)(bp + 4);
            }
            int4 hi, lo;
            cvt8(b0, b1, hi, lo);
            *(int4*)&sm.st[w][2][e][ko] = hi;
            *(int4*)&sm.st[w][3][e][ko] = lo;
        }
        if (m < 3) loadA(k0 + 32);   // prefetch next k-step's globals (regs only)
        // fragments + MFMA (in-order LDS guarantees staging writes landed)
        bf16x8 ah[4], al[4], bh[4], bl[4];
#pragma unroll
        for (int i = 0; i < 4; ++i) {
            ah[i] = *(const bf16x8*)&sm.st[w][0][16 * i + fr][fk];
            al[i] = *(const bf16x8*)&sm.st[w][1][16 * i + fr][fk];
            bh[i] = *(const bf16x8*)&sm.st[w][2][16 * i + fr][fk];
            bl[i] = *(const bf16x8*)&sm.st[w][3][16 * i + fr][fk];
        }
#pragma unroll
        for (int i = 0; i < 4; ++i)
#pragma unroll
            for (int j = 0; j < 4; ++j) {
                acc[i][j] = __builtin_amdgcn_mfma_f32_16x16x32_bf16(ah[i], bh[j], acc[i][j], 0, 0, 0);
                acc[i][j] = __builtin_amdgcn_mfma_f32_16x16x32_bf16(ah[i], bl[j], acc[i][j], 0, 0, 0);
                acc[i][j] = __builtin_amdgcn_mfma_f32_16x16x32_bf16(al[i], bh[j], acc[i][j], 0, 0, 0);
            }
    }
    // epilogue: cross-wave reduce (red aliases st -> barrier first)
    __syncthreads();
    const int orow = (lane >> 4) * 4;
#pragma unroll
    for (int i = 0; i < 4; ++i)
#pragma unroll
        for (int j = 0; j < 4; ++j)
#pragma unroll
            for (int q = 0; q < 4; ++q)
                sm.red[w][(16 * i + orow + q) * 64 + 16 * j + fr] = acc[i][j][q];
    __syncthreads();
#pragma unroll
    for (int rep = 0; rep < 4; ++rep) {
        const int idx4 = rep * 256 + tid;
        const int row = idx4 >> 4, col = (idx4 & 15) * 4;
        const int gn = n0 + col;
        if (gn < NDBC) {
            const float4 s0 = *(const float4*)&sm.red[0][row * 64 + col];
            const float4 s1 = *(const float4*)&sm.red[1][row * 64 + col];
            const float4 s2 = *(const float4*)&sm.red[2][row * 64 + col];
            const float4 s3 = *(const float4*)&sm.red[3][row * 64 + col];
            *(float4*)(dBC + (size_t)(m0 + row) * NDBC + gn) = make_float4(
                s0.x + s1.x + s2.x + s3.x, s0.y + s1.y + s2.y + s3.y,
                s0.z + s1.z + s2.z + s3.z, s0.w + s1.w + s2.w + s3.w);
        }
    }
}

// ---------------------------------------------------------------------------
// gemm3 (MFMA, wave-split-K, direct-from-global): out[tok][e] = g · W_out^T
// M=1152 N=256 K=512. Grid (4,18); wave w owns k in [128w,+128). No LDS in
// the main loop (A = packed bf16-split g, B = W_out cvt in-register).
// Epilogue: cross-wave LDS reduce -> out directly.
// ---------------------------------------------------------------------------
__global__ __launch_bounds__(256) void gemm3_mfma(const unsigned* __restrict__ gpk,
                                                  const float* __restrict__ W_out,
                                                  float* __restrict__ out) {
    __shared__ float red[4][4096];
    const int tid = threadIdx.x;
    const int n0 = blockIdx.x * 64, m0 = blockIdx.y * 64;
    const int w = tid >> 6, lane = tid & 63;
    const int kw = w * 128;
    const int fr = lane & 15, fk = (lane >> 4) * 8;
    f32x4 acc[4][4] = {};
#pragma unroll
    for (int m = 0; m < 4; ++m) {
        const int k0 = kw + m * 32;
        bf16x8 ah[4], al[4], bh[4], bl[4];
#pragma unroll
        for (int i = 0; i < 4; ++i) {
            const unsigned* ap = gpk + (size_t)(m0 + 16 * i + fr) * D_INNER + k0 + fk;
            unpack8(*(const int4*)ap, *(const int4*)(ap + 4), ah[i], al[i]);
        }
#pragma unroll
        for (int j = 0; j < 4; ++j) {
            const float* bp = W_out + (size_t)(n0 + 16 * j + fr) * D_INNER + k0 + fk;
            int4 hi, lo;
            cvt8(*(const float4*)bp, *(const float4*)(bp + 4), hi, lo);
            bh[j] = *(bf16x8*)&hi;
            bl[j] = *(bf16x8*)&lo;
        }
#pragma unroll
        for (int i = 0; i < 4; ++i)
#pragma unroll
            for (int j = 0; j < 4; ++j) {
                acc[i][j] = __builtin_amdgcn_mfma_f32_16x16x32_bf16(ah[i], bh[j], acc[i][j], 0, 0, 0);
                acc[i][j] = __builtin_amdgcn_mfma_f32_16x16x32_bf16(ah[i], bl[j], acc[i][j], 0, 0, 0);
                acc[i][j] = __builtin_amdgcn_mfma_f32_16x16x32_bf16(al[i], bh[j], acc[i][j], 0, 0, 0);
            }
    }
    const int orow = (lane >> 4) * 4;
#pragma unroll
    for (int i = 0; i < 4; ++i)
#pragma unroll
        for (int j = 0; j < 4; ++j)
#pragma unroll
            for (int q = 0; q < 4; ++q)
                red[w][(16 * i + orow + q) * 64 + 16 * j + fr] = acc[i][j][q];
    __syncthreads();
#pragma unroll
    for (int rep = 0; rep < 4; ++rep) {
        const int idx4 = rep * 256 + tid;
        const int row = idx4 >> 4, col = (idx4 & 15) * 4;
        const float4 s0 = *(const float4*)&red[0][row * 64 + col];
        const float4 s1 = *(const float4*)&red[1][row * 64 + col];
        const float4 s2 = *(const float4*)&red[2][row * 64 + col];
        const float4 s3 = *(const float4*)&red[3][row * 64 + col];
        *(float4*)(out + (size_t)(m0 + row) * D_MODEL + n0 + col) = make_float4(
            s0.x + s1.x + s2.x + s3.x, s0.y + s1.y + s2.y + s3.y,
            s0.z + s1.z + s2.z + s3.z, s0.w + s1.w + s2.w + s3.w);
    }
}

// ---------------------------------------------------------------------------
// Fused aux+scan (R4/R8-verified structure). One wave per (b,d); lane = state n.
// Epilogue emits g as ONE packed u32 (bf16 hi<<16 | lo) per token at [tok][d].
// ---------------------------------------------------------------------------
__device__ __forceinline__ float bcast(const float v, const int i) {
    return __int_as_float(__builtin_amdgcn_readlane(__float_as_int(v), i));
}

template<int CNT>
__device__ __forceinline__ void scan_chunk(const float* __restrict__ dBC,
                                           const float* __restrict__ xz,
                                           unsigned* __restrict__ gpk,
                                           float (*__restrict__ Pw)[65],
                                           const int d, const int base, const int t0,
                                           const float An2, const float4 wdt,
                                           const float bdt, const float dpv,
                                           const float4 cw4, const float cbv,
                                           const int lane, float& h) {
    float delta_r = 0.f, dix_r = 0.f, dpix_r = 0.f, sz_r = 0.f;
    if (lane < CNT) {
        const int t = t0 + lane;
        const int tok = base + t;
        const float* row = xz + (size_t)d * NTOK + tok;
        float s0 = cbv;
        if (t >= 2) s0 = fmaf(cw4.x, row[-2], s0);
        if (t >= 1) s0 = fmaf(cw4.y, row[-1], s0);
        s0 = fmaf(cw4.z, row[0], s0);
        if (t < L_SEQ - 1) s0 = fmaf(cw4.w, row[1], s0);
        const float ixv = s0 * __builtin_amdgcn_rcpf(1.f + __expf(-s0));

        const float4 dt4 = *(const float4*)(dBC + (size_t)tok * NDBC);
        float s = fmaf(dt4.x, wdt.x, bdt);
        s = fmaf(dt4.y, wdt.y, s);
        s = fmaf(dt4.z, wdt.z, s);
        s = fmaf(dt4.w, wdt.w, s);
        const float delta = fmaxf(s, 0.f) + __logf(1.f + __expf(-fabsf(s)));
        const float zv = xz[(size_t)(D_INNER + d) * NTOK + tok];
        delta_r = delta;
        dix_r   = delta * ixv;
        dpix_r  = dpv * ixv;
        sz_r    = zv * __builtin_amdgcn_rcpf(1.f + __expf(-zv));
    }
#pragma unroll
    for (int i = 0; i < CNT; ++i) {
        const float2 bc = *(const float2*)(dBC + (size_t)(base + t0 + i) * NDBC
                                           + DT_RANK + 2 * lane);
        const float dlt = bcast(delta_r, i);
        const float dxv = bcast(dix_r, i);
        const float dA = __builtin_amdgcn_exp2f(dlt * An2);
        h = fmaf(dA, h, dxv * bc.x);
        Pw[i][lane] = h * bc.y;
    }
    const int tl = lane & 31, hf = lane >> 5;
    float s2 = 0.f;
    if (tl < CNT) {
#pragma unroll
        for (int j = 0; j < 32; ++j) s2 += Pw[tl][hf * 32 + j];
    }
    s2 += __shfl_xor(s2, 32, 64);
    if (hf == 0 && tl < CNT) {
        const float g = (s2 + dpix_r) * sz_r;
        const unsigned u = __float_as_uint(g);
        const unsigned t = u + 0x7FFFu + ((u >> 16) & 1u);
        const unsigned lo16 = __float_as_uint(
            g - __uint_as_float(t & 0xFFFF0000u)) >> 16;
        gpk[(size_t)(base + t0 + tl) * D_INNER + d] = (t & 0xFFFF0000u) | lo16;
    }
}

__global__ __launch_bounds__(256) void scan_k(const float* __restrict__ dBC,
                                              const float* __restrict__ xz,
                                              const float* __restrict__ W_dt,
                                              const float* __restrict__ b_dt,
                                              const float* __restrict__ A_log,
                                              const float* __restrict__ Dp,
                                              const float* __restrict__ conv_w,
                                              const float* __restrict__ conv_b,
                                              unsigned* __restrict__ gpk) {
    __shared__ float P[4][32][65];
    const int w = threadIdx.x >> 6, lane = threadIdx.x & 63;
    const int b = blockIdx.x >> 7, dg = blockIdx.x & 127;
    const int d = (dg << 2) | w;
    const int base = b * L_SEQ;
    const float An2 = -__expf(A_log[(d << 6) + lane]) * 1.44269504088896f;
    const float4 wdt = *(const float4*)(W_dt + (d << 2));
    const float bdt = b_dt[d], dpv = Dp[d];
    const float4 cw4 = *(const float4*)(conv_w + (d << 2));
    const float cbv = conv_b[d];
    float h = 0.f;
    scan_chunk<32>(dBC, xz, gpk, P[w], d, base, 0,   An2, wdt, bdt, dpv, cw4, cbv, lane, h);
    scan_chunk<32>(dBC, xz, gpk, P[w], d, base, 32,  An2, wdt, bdt, dpv, cw4, cbv, lane, h);
    scan_chunk<32>(dBC, xz, gpk, P[w], d, base, 64,  An2, wdt, bdt, dpv, cw4, cbv, lane, h);
    scan_chunk<32>(dBC, xz, gpk, P[w], d, base, 96,  An2, wdt, bdt, dpv, cw4, cbv, lane, h);
    scan_chunk<16>(dBC, xz, gpk, P[w], d, base, 128, An2, wdt, bdt, dpv, cw4, cbv, lane, h);
}

// ---------------------------------------------------------------------------
extern "C" void kernel_launch(void* const* d_in, const int* in_sizes, int n_in,
                              void* d_out, int out_size, void* d_ws, size_t ws_size,
                              hipStream_t stream) {
    const float* x      = (const float*)d_in[0];
    // d_in[1] = lastin (unused: reference starts from h0 = 0)
    const float* W_in   = (const float*)d_in[2];
    const float* conv_w = (const float*)d_in[3];
    const float* conv_b = (const float*)d_in[4];
    const float* W_x    = (const float*)d_in[5];
    const float* W_dt   = (const float*)d_in[6];
    const float* b_dt   = (const float*)d_in[7];
    const float* A_log  = (const float*)d_in[8];
    const float* Dp     = (const float*)d_in[9];
    const float* W_out  = (const float*)d_in[10];
    float* out = (float*)d_out;

    float* ws  = (float*)d_ws;
    float* xz  = ws;                          // [1024][1152] = 1,179,648 f
    float* dBC = xz + 1179648;                // [1152][132]  =   152,064 f (B/C interleaved)
    unsigned* gpk = (unsigned*)(dBC + 152064); // [1152][512] packed bf16 pair

    // 1) xz = W_in · x^T   (MFMA bf16-split-3, single-pass K=256)
    gemm1_mfma<<<dim3(18, 16), 256, 0, stream>>>(W_in, x, xz);
    // 2) dBC = silu(conv(xz)) · W_x[perm]^T  (MFMA, wave-split-K, in-block reduce)
    gemm2_mfma<<<dim3(3, 18), 256, 0, stream>>>(xz, W_x, dBC, conv_w, conv_b);
    // 3) fused conv + aux + scan -> g packed bf16-split [tok][d]
    scan_k<<<dim3(B_SZ * 128), 256, 0, stream>>>(dBC, xz, W_dt, b_dt, A_log, Dp,
                                                 conv_w, conv_b, gpk);
    // 4) out = g · W_out^T  (MFMA, wave-split-K, in-block reduce)
    gemm3_mfma<<<dim3(4, 18), 256, 0, stream>>>(gpk, W_out, out);
}

// Round 10
// 129.584 us; speedup vs baseline: 1.1088x; 1.1088x over previous
//
#include <hip/hip_runtime.h>

#define B_SZ 8
#define L_SEQ 144
#define NTOK 1152
#define D_MODEL 256
#define D_INNER 512
#define D_STATE 64
#define DT_RANK 4
#define NDBC 132
#define SLAB 152064      // NTOK*NDBC: one split-K slab of dBC

typedef __attribute__((ext_vector_type(8))) short bf16x8;
typedef __attribute__((ext_vector_type(4))) float f32x4;

// fp32 -> bf16-split (hi = RNE bf16, lo = trunc bf16 of residual), packed
// into int4 pairs for 16B LDS/register traffic.
__device__ __forceinline__ void cvt8(const float4& f0, const float4& f1,
                                     int4& hi, int4& lo) {
    const float f[8] = {f0.x, f0.y, f0.z, f0.w, f1.x, f1.y, f1.z, f1.w};
    unsigned h[8], l[8];
#pragma unroll
    for (int e = 0; e < 8; ++e) {
        const unsigned u = __float_as_uint(f[e]);
        const unsigned t = u + 0x7FFFu + ((u >> 16) & 1u);
        h[e] = t >> 16;
        l[e] = __float_as_uint(f[e] - __uint_as_float(t & 0xFFFF0000u)) >> 16;
    }
    hi = make_int4((int)(h[0] | (h[1] << 16)), (int)(h[2] | (h[3] << 16)),
                   (int)(h[4] | (h[5] << 16)), (int)(h[6] | (h[7] << 16)));
    lo = make_int4((int)(l[0] | (l[1] << 16)), (int)(l[2] | (l[3] << 16)),
                   (int)(l[4] | (l[5] << 16)), (int)(l[6] | (l[7] << 16)));
}

// unpack 8 packed u32 (hi<<16|lo) into hi/lo bf16x8 fragments
__device__ __forceinline__ void unpack8(const int4& p0, const int4& p1,
                                        bf16x8& hv, bf16x8& lv) {
    const unsigned u[8] = {(unsigned)p0.x, (unsigned)p0.y, (unsigned)p0.z,
                           (unsigned)p0.w, (unsigned)p1.x, (unsigned)p1.y,
                           (unsigned)p1.z, (unsigned)p1.w};
    int h[4], l[4];
#pragma unroll
    for (int i = 0; i < 4; ++i) {
        h[i] = (int)((u[2 * i] >> 16) | (u[2 * i + 1] & 0xFFFF0000u));
        l[i] = (int)((u[2 * i] & 0xFFFFu) | (u[2 * i + 1] << 16));
    }
    hv = *(bf16x8*)h;
    lv = *(bf16x8*)l;
}

__device__ __forceinline__ int bc_perm(const int p) {
    // stored position p -> original W_x row ([dt(4) | B0 C0 B1 C1 ...])
    return (p < DT_RANK) ? p
         : (((p - DT_RANK) & 1) ? (DT_RANK + D_STATE + ((p - DT_RANK) >> 1))
                                : (DT_RANK + ((p - DT_RANK) >> 1)));
}

// ---------------------------------------------------------------------------
// gemm1 (MFMA): xz[e][tok] = W_in[e][:] · x[tok][:]   M=1024 N=1152 K=256
// bf16-split-3: D = Ah·Bh + Ah·Bl + Al·Bh, fp32 accumulate. (R7/R8-verified)
// ---------------------------------------------------------------------------
#define LW 40
__global__ __launch_bounds__(256) void gemm1_mfma(const float* __restrict__ W_in,
                                                  const float* __restrict__ x,
                                                  float* __restrict__ xz) {
    __shared__ unsigned short Ah[64][LW], Al[64][LW], Bh[64][LW], Bl[64][LW];
    const int tid = threadIdx.x;
    const int m0 = blockIdx.y * 64, n0 = blockIdx.x * 64;
    const int r = tid >> 2, kq = (tid & 3) * 8;        // staging: row, k-offset
    const int w = tid >> 6, lane = tid & 63;
    const int wm = (w & 1) * 32, wn = (w >> 1) * 32;   // wave tile origin
    const int fr = lane & 15, fk = (lane >> 4) * 8;    // fragment row / k-group
    f32x4 acc[2][2] = {};
    float4 a0, a1, b0, b1;

    auto loadG = [&](const int k0) {
        const float* ap = W_in + (size_t)(m0 + r) * D_MODEL + k0 + kq;
        const float* bp = x    + (size_t)(n0 + r) * D_MODEL + k0 + kq;
        a0 = *(const float4*)ap; a1 = *(const float4*)(ap + 4);
        b0 = *(const float4*)bp; b1 = *(const float4*)(bp + 4);
    };

    loadG(0);
    for (int k0 = 0; k0 < D_MODEL; k0 += 32) {
        int4 hi, lo;
        __syncthreads();
        cvt8(a0, a1, hi, lo);
        *(int4*)&Ah[r][kq] = hi; *(int4*)&Al[r][kq] = lo;
        cvt8(b0, b1, hi, lo);
        *(int4*)&Bh[r][kq] = hi; *(int4*)&Bl[r][kq] = lo;
        __syncthreads();
        if (k0 + 32 < D_MODEL) loadG(k0 + 32);   // register prefetch
        bf16x8 ah[2], al[2], bh[2], bl[2];
#pragma unroll
        for (int i = 0; i < 2; ++i) {
            ah[i] = *(const bf16x8*)&Ah[wm + 16 * i + fr][fk];
            al[i] = *(const bf16x8*)&Al[wm + 16 * i + fr][fk];
            bh[i] = *(const bf16x8*)&Bh[wn + 16 * i + fr][fk];
            bl[i] = *(const bf16x8*)&Bl[wn + 16 * i + fr][fk];
        }
#pragma unroll
        for (int i = 0; i < 2; ++i)
#pragma unroll
            for (int j = 0; j < 2; ++j) {
                acc[i][j] = __builtin_amdgcn_mfma_f32_16x16x32_bf16(ah[i], bh[j], acc[i][j], 0, 0, 0);
                acc[i][j] = __builtin_amdgcn_mfma_f32_16x16x32_bf16(ah[i], bl[j], acc[i][j], 0, 0, 0);
                acc[i][j] = __builtin_amdgcn_mfma_f32_16x16x32_bf16(al[i], bh[j], acc[i][j], 0, 0, 0);
            }
    }
    const int orow = (lane >> 4) * 4;   // C/D: col = lane&15, row = (lane>>4)*4+reg
#pragma unroll
    for (int i = 0; i < 2; ++i)
#pragma unroll
        for (int j = 0; j < 2; ++j)
#pragma unroll
            for (int q = 0; q < 4; ++q)
                xz[(size_t)(m0 + wm + 16 * i + orow + q) * NTOK
                   + n0 + wn + 16 * j + fr] = acc[i][j][q];
}

// ---------------------------------------------------------------------------
// gemm2 (MFMA): sl3[z][tok][p] = silu(conv(xz))[tok][:] · W_x[perm(p)][:]
// M=1152(tok) N=132(GN) K=512(d), split-K=8 (2 k-steps of 32). (R8-verified)
// ---------------------------------------------------------------------------
__global__ __launch_bounds__(256) void gemm2_mfma(const float* __restrict__ xz,
                                                  const float* __restrict__ W_x,
                                                  float* __restrict__ slab,
                                                  const float* __restrict__ cw,
                                                  const float* __restrict__ cb) {
    __shared__ unsigned short Ah[64][LW], Al[64][LW], Bh[64][LW], Bl[64][LW];
    const int tid = threadIdx.x;
    const int n0 = blockIdx.x * 64;      // e-cols (0,64,128)
    const int m0 = blockIdx.y * 64;      // toks
    const int kbeg = blockIdx.z * 64;    // d-slab
    const int ar = tid >> 3, ac8 = (tid & 7) * 8;   // A: d-row, tok-octet
    const int br = tid >> 2, bq8 = (tid & 3) * 8;   // B: e-row, k-octet
    const int brow = bc_perm(n0 + br);   // used only when n0+br < 132
    const int w = tid >> 6, lane = tid & 63;
    const int wm = (w & 1) * 32, wn = (w >> 1) * 32;
    const int fr = lane & 15, fk = (lane >> 4) * 8;
    const int t = (m0 + ac8) % L_SEQ;    // octet never straddles a sequence
    f32x4 acc[2][2] = {};
    slab += (size_t)blockIdx.z * SLAB;

#pragma unroll
    for (int ks = 0; ks < 2; ++ks) {
        const int k0 = kbeg + ks * 32;
        const int d = k0 + ar;
        const float* row = xz + (size_t)d * NTOK + m0 + ac8;
        const float4 a0 = *(const float4*)row;
        const float4 a1 = *(const float4*)(row + 4);
        const float xm2 = (t > 0) ? row[-2] : 0.f;            // left pad
        const float xm1 = (t > 0) ? row[-1] : 0.f;
        const float xp8 = (t < L_SEQ - 8) ? row[8] : 0.f;     // right pad
        const float4 cw4 = *(const float4*)(cw + d * 4);
        const float cbv = cb[d];
        float4 bv0 = make_float4(0.f, 0.f, 0.f, 0.f), bv1 = bv0;
        if (n0 + br < NDBC) {
            const float* bp = W_x + (size_t)brow * D_INNER + k0 + bq8;
            bv0 = *(const float4*)bp; bv1 = *(const float4*)(bp + 4);
        }
        __syncthreads();   // previous step's fragment reads complete
        {
            const float in[11] = {xm2, xm1, a0.x, a0.y, a0.z, a0.w,
                                  a1.x, a1.y, a1.z, a1.w, xp8};
#pragma unroll
            for (int j = 0; j < 8; ++j) {
                float s = cbv;
                s = fmaf(cw4.x, in[j + 0], s);
                s = fmaf(cw4.y, in[j + 1], s);
                s = fmaf(cw4.z, in[j + 2], s);
                s = fmaf(cw4.w, in[j + 3], s);
                const float g = s * __builtin_amdgcn_rcpf(1.f + __expf(-s));
                const unsigned u = __float_as_uint(g);
                const unsigned tt = u + 0x7FFFu + ((u >> 16) & 1u);
                Ah[ac8 + j][ar] = (unsigned short)(tt >> 16);
                Al[ac8 + j][ar] = (unsigned short)(__float_as_uint(
                                     g - __uint_as_float(tt & 0xFFFF0000u)) >> 16);
            }
            int4 hi, lo;
            cvt8(bv0, bv1, hi, lo);
            *(int4*)&Bh[br][bq8] = hi; *(int4*)&Bl[br][bq8] = lo;
        }
        __syncthreads();
        bf16x8 ah[2], al[2], bh[2], bl[2];
#pragma unroll
        for (int i = 0; i < 2; ++i) {
            ah[i] = *(const bf16x8*)&Ah[wm + 16 * i + fr][fk];
            al[i] = *(const bf16x8*)&Al[wm + 16 * i + fr][fk];
            bh[i] = *(const bf16x8*)&Bh[wn + 16 * i + fr][fk];
            bl[i] = *(const bf16x8*)&Bl[wn + 16 * i + fr][fk];
        }
#pragma unroll
        for (int i = 0; i < 2; ++i)
#pragma unroll
            for (int j = 0; j < 2; ++j) {
                acc[i][j] = __builtin_amdgcn_mfma_f32_16x16x32_bf16(ah[i], bh[j], acc[i][j], 0, 0, 0);
                acc[i][j] = __builtin_amdgcn_mfma_f32_16x16x32_bf16(ah[i], bl[j], acc[i][j], 0, 0, 0);
                acc[i][j] = __builtin_amdgcn_mfma_f32_16x16x32_bf16(al[i], bh[j], acc[i][j], 0, 0, 0);
            }
    }
    const int orow = (lane >> 4) * 4;
#pragma unroll
    for (int i = 0; i < 2; ++i)
#pragma unroll
        for (int j = 0; j < 2; ++j) {
            const int gn = n0 + wn + 16 * j + fr;
            if (gn < NDBC)
#pragma unroll
                for (int q = 0; q < 4; ++q)
                    slab[(size_t)(m0 + wm + 16 * i + orow + q) * NDBC + gn]
                        = acc[i][j][q];
        }
}

// ---------------------------------------------------------------------------
// gemm3 (MFMA, fused in-block split-K): out[tok][e] = g[tok][:] · W_out[e][:]
// M=1152 N=256 K=512. Grid (4, 72) = 288 blocks (healthy occupancy level).
// Block = 16-tok x 64-e tile; wave w owns k in [128w, 128w+128) (4 k-steps).
// Main loop identical per-op to R8 (gpk unpack + in-register W_out cvt, no
// LDS). Epilogue: 4-wave LDS reduce of the 16x64 tile -> out directly.
// Removes the sl6 slabs (18.8 MB round-trip) and the reduce8 dispatch.
// ---------------------------------------------------------------------------
__global__ __launch_bounds__(256) void gemm3_mfma(const unsigned* __restrict__ gpk,
                                                  const float* __restrict__ W_out,
                                                  float* __restrict__ out) {
    __shared__ float red[4][16][64];
    const int tid = threadIdx.x;
    const int n0 = blockIdx.x * 64, m0 = blockIdx.y * 16;
    const int w = tid >> 6, lane = tid & 63;
    const int kw = w * 128;
    const int fr = lane & 15, fk = (lane >> 4) * 8;
    f32x4 acc[4] = {};
#pragma unroll
    for (int m = 0; m < 4; ++m) {
        const int k0 = kw + m * 32;
        bf16x8 ah, al, bh[4], bl[4];
        const unsigned* ap = gpk + (size_t)(m0 + fr) * D_INNER + k0 + fk;
        unpack8(*(const int4*)ap, *(const int4*)(ap + 4), ah, al);
#pragma unroll
        for (int j = 0; j < 4; ++j) {
            const float* bp = W_out + (size_t)(n0 + 16 * j + fr) * D_INNER + k0 + fk;
            int4 hi, lo;
            cvt8(*(const float4*)bp, *(const float4*)(bp + 4), hi, lo);
            bh[j] = *(bf16x8*)&hi;
            bl[j] = *(bf16x8*)&lo;
        }
#pragma unroll
        for (int j = 0; j < 4; ++j) {
            acc[j] = __builtin_amdgcn_mfma_f32_16x16x32_bf16(ah, bh[j], acc[j], 0, 0, 0);
            acc[j] = __builtin_amdgcn_mfma_f32_16x16x32_bf16(ah, bl[j], acc[j], 0, 0, 0);
            acc[j] = __builtin_amdgcn_mfma_f32_16x16x32_bf16(al, bh[j], acc[j], 0, 0, 0);
        }
    }
    const int orow = (lane >> 4) * 4;   // C/D: col = lane&15, row = (lane>>4)*4+reg
#pragma unroll
    for (int j = 0; j < 4; ++j)
#pragma unroll
        for (int q = 0; q < 4; ++q)
            red[w][orow + q][16 * j + fr] = acc[j][q];
    __syncthreads();
    // cross-wave reduce (left-assoc w0+w1+w2+w3), one float4 per thread
    const int row = tid >> 4, col = (tid & 15) * 4;
    const float4 s0 = *(const float4*)&red[0][row][col];
    const float4 s1 = *(const float4*)&red[1][row][col];
    const float4 s2 = *(const float4*)&red[2][row][col];
    const float4 s3 = *(const float4*)&red[3][row][col];
    *(float4*)(out + (size_t)(m0 + row) * D_MODEL + n0 + col) = make_float4(
        s0.x + s1.x + s2.x + s3.x, s0.y + s1.y + s2.y + s3.y,
        s0.z + s1.z + s2.z + s3.z, s0.w + s1.w + s2.w + s3.w);
}

// ---------------------------------------------------------------------------
// Split-K slab reduction: out[i] = sum_{s<8} in[i + s*s4], left-associated.
// ---------------------------------------------------------------------------
__global__ __launch_bounds__(256) void reduce8_k(const float4* __restrict__ in,
                                                 float4* __restrict__ out,
                                                 const int n4, const int s4) {
    const int i = blockIdx.x * 256 + threadIdx.x;
    if (i >= n4) return;
    float4 a = in[i];
#pragma unroll
    for (int s = 1; s < 8; ++s) {
        const float4 b = in[i + s * s4];
        a.x += b.x; a.y += b.y; a.z += b.z; a.w += b.w;
    }
    out[i] = a;
}

// ---------------------------------------------------------------------------
// Fused aux+scan (R4/R8-verified structure). One wave per (b,d); lane = state n.
// Epilogue emits g as ONE packed u32 (bf16 hi<<16 | lo) per token at [tok][d].
// ---------------------------------------------------------------------------
__device__ __forceinline__ float bcast(const float v, const int i) {
    return __int_as_float(__builtin_amdgcn_readlane(__float_as_int(v), i));
}

template<int CNT>
__device__ __forceinline__ void scan_chunk(const float* __restrict__ dBC,
                                           const float* __restrict__ xz,
                                           unsigned* __restrict__ gpk,
                                           float (*__restrict__ Pw)[65],
                                           const int d, const int base, const int t0,
                                           const float An2, const float4 wdt,
                                           const float bdt, const float dpv,
                                           const float4 cw4, const float cbv,
                                           const int lane, float& h) {
    float delta_r = 0.f, dix_r = 0.f, dpix_r = 0.f, sz_r = 0.f;
    if (lane < CNT) {
        const int t = t0 + lane;
        const int tok = base + t;
        const float* row = xz + (size_t)d * NTOK + tok;
        float s0 = cbv;
        if (t >= 2) s0 = fmaf(cw4.x, row[-2], s0);
        if (t >= 1) s0 = fmaf(cw4.y, row[-1], s0);
        s0 = fmaf(cw4.z, row[0], s0);
        if (t < L_SEQ - 1) s0 = fmaf(cw4.w, row[1], s0);
        const float ixv = s0 * __builtin_amdgcn_rcpf(1.f + __expf(-s0));

        const float4 dt4 = *(const float4*)(dBC + (size_t)tok * NDBC);
        float s = fmaf(dt4.x, wdt.x, bdt);
        s = fmaf(dt4.y, wdt.y, s);
        s = fmaf(dt4.z, wdt.z, s);
        s = fmaf(dt4.w, wdt.w, s);
        const float delta = fmaxf(s, 0.f) + __logf(1.f + __expf(-fabsf(s)));
        const float zv = xz[(size_t)(D_INNER + d) * NTOK + tok];
        delta_r = delta;
        dix_r   = delta * ixv;
        dpix_r  = dpv * ixv;
        sz_r    = zv * __builtin_amdgcn_rcpf(1.f + __expf(-zv));
    }
#pragma unroll
    for (int i = 0; i < CNT; ++i) {
        const float2 bc = *(const float2*)(dBC + (size_t)(base + t0 + i) * NDBC
                                           + DT_RANK + 2 * lane);
        const float dlt = bcast(delta_r, i);
        const float dxv = bcast(dix_r, i);
        const float dA = __builtin_amdgcn_exp2f(dlt * An2);
        h = fmaf(dA, h, dxv * bc.x);
        Pw[i][lane] = h * bc.y;
    }
    const int tl = lane & 31, hf = lane >> 5;
    float s2 = 0.f;
    if (tl < CNT) {
#pragma unroll
        for (int j = 0; j < 32; ++j) s2 += Pw[tl][hf * 32 + j];
    }
    s2 += __shfl_xor(s2, 32, 64);
    if (hf == 0 && tl < CNT) {
        const float g = (s2 + dpix_r) * sz_r;
        const unsigned u = __float_as_uint(g);
        const unsigned t = u + 0x7FFFu + ((u >> 16) & 1u);
        const unsigned lo16 = __float_as_uint(
            g - __uint_as_float(t & 0xFFFF0000u)) >> 16;
        gpk[(size_t)(base + t0 + tl) * D_INNER + d] = (t & 0xFFFF0000u) | lo16;
    }
}

__global__ __launch_bounds__(256) void scan_k(const float* __restrict__ dBC,
                                              const float* __restrict__ xz,
                                              const float* __restrict__ W_dt,
                                              const float* __restrict__ b_dt,
                                              const float* __restrict__ A_log,
                                              const float* __restrict__ Dp,
                                              const float* __restrict__ conv_w,
                                              const float* __restrict__ conv_b,
                                              unsigned* __restrict__ gpk) {
    __shared__ float P[4][32][65];
    const int w = threadIdx.x >> 6, lane = threadIdx.x & 63;
    const int b = blockIdx.x >> 7, dg = blockIdx.x & 127;
    const int d = (dg << 2) | w;
    const int base = b * L_SEQ;
    const float An2 = -__expf(A_log[(d << 6) + lane]) * 1.44269504088896f;
    const float4 wdt = *(const float4*)(W_dt + (d << 2));
    const float bdt = b_dt[d], dpv = Dp[d];
    const float4 cw4 = *(const float4*)(conv_w + (d << 2));
    const float cbv = conv_b[d];
    float h = 0.f;
    scan_chunk<32>(dBC, xz, gpk, P[w], d, base, 0,   An2, wdt, bdt, dpv, cw4, cbv, lane, h);
    scan_chunk<32>(dBC, xz, gpk, P[w], d, base, 32,  An2, wdt, bdt, dpv, cw4, cbv, lane, h);
    scan_chunk<32>(dBC, xz, gpk, P[w], d, base, 64,  An2, wdt, bdt, dpv, cw4, cbv, lane, h);
    scan_chunk<32>(dBC, xz, gpk, P[w], d, base, 96,  An2, wdt, bdt, dpv, cw4, cbv, lane, h);
    scan_chunk<16>(dBC, xz, gpk, P[w], d, base, 128, An2, wdt, bdt, dpv, cw4, cbv, lane, h);
}

// ---------------------------------------------------------------------------
extern "C" void kernel_launch(void* const* d_in, const int* in_sizes, int n_in,
                              void* d_out, int out_size, void* d_ws, size_t ws_size,
                              hipStream_t stream) {
    const float* x      = (const float*)d_in[0];
    // d_in[1] = lastin (unused: reference starts from h0 = 0)
    const float* W_in   = (const float*)d_in[2];
    const float* conv_w = (const float*)d_in[3];
    const float* conv_b = (const float*)d_in[4];
    const float* W_x    = (const float*)d_in[5];
    const float* W_dt   = (const float*)d_in[6];
    const float* b_dt   = (const float*)d_in[7];
    const float* A_log  = (const float*)d_in[8];
    const float* Dp     = (const float*)d_in[9];
    const float* W_out  = (const float*)d_in[10];
    float* out = (float*)d_out;

    float* ws  = (float*)d_ws;
    float* xz  = ws;                          // [1024][1152] = 1,179,648 f
    float* dBC = xz + 1179648;                // [1152][132]  =   152,064 f (B/C interleaved)
    float* sl3 = dBC + 152064;                // 8 x 152,064  = 1,216,512 f
    unsigned* gpk = (unsigned*)(sl3 + 8 * SLAB);   // [1152][512] packed bf16 pair

    // 1) xz = W_in · x^T   (MFMA bf16-split-3, single-pass K=256)
    gemm1_mfma<<<dim3(18, 16), 256, 0, stream>>>(W_in, x, xz);
    // 2) sl3[z][tok][p] = silu(conv(xz)) · W_x[perm(p)]  (MFMA, conv in staging,
    //    B/C interleave, split-K=8)
    gemm2_mfma<<<dim3(3, 18, 8), 256, 0, stream>>>(xz, W_x, sl3, conv_w, conv_b);
    reduce8_k<<<dim3(149), 256, 0, stream>>>((const float4*)sl3, (float4*)dBC,
                                             NTOK * NDBC / 4, NTOK * NDBC / 4);
    // 3) fused conv + aux + scan -> g packed bf16-split [tok][d]
    scan_k<<<dim3(B_SZ * 128), 256, 0, stream>>>(dBC, xz, W_dt, b_dt, A_log, Dp,
                                                 conv_w, conv_b, gpk);
    // 4) out = g · W_out^T  (MFMA, in-block split-K over waves, direct write)
    gemm3_mfma<<<dim3(4, 72), 256, 0, stream>>>(gpk, W_out, out);
}